// Round 9
// baseline (525.913 us; speedup 1.0000x reference)
//
#include <hip/hip_runtime.h>
#include <stdint.h>

#define N_ROWS 4096
#define D_DIM  1024
#define N_CAND 8192
#define TEMP_INV 20.0f

#define BM 256
#define BN 256
#define BK 64
#define NT 16  // K-tiles

typedef __attribute__((ext_vector_type(4)))  int   i32x4;
typedef __attribute__((ext_vector_type(8)))  int   i32x8;
typedef __attribute__((ext_vector_type(16))) float f32x16;

using gvoid = __attribute__((address_space(1))) void;
using lvoid = __attribute__((address_space(3))) void;

#define BAR() __builtin_amdgcn_s_barrier()
#define SCHED0() __builtin_amdgcn_sched_barrier(0)

// ---------------------------------------------------------------------------
// Kernel 1: normalize rows, convert to fp8 e4m3 (natural column order).
// cand = [P; N]. Also zeroes rowsum.
// ---------------------------------------------------------------------------
__global__ __launch_bounds__(256) void prep_kernel(
    const float* __restrict__ s, const float* __restrict__ p,
    const float* __restrict__ ng, unsigned char* __restrict__ s_q,
    unsigned char* __restrict__ cand_q, float* __restrict__ rowsum) {
  const int row = blockIdx.x;
  const int t = threadIdx.x;
  const float* src;
  unsigned char* dst;
  if (row < N_ROWS) {
    src = s + (size_t)row * D_DIM;
    dst = s_q + (size_t)row * D_DIM;
  } else if (row < 2 * N_ROWS) {
    src = p + (size_t)(row - N_ROWS) * D_DIM;
    dst = cand_q + (size_t)(row - N_ROWS) * D_DIM;
  } else {
    src = ng + (size_t)(row - 2 * N_ROWS) * D_DIM;
    dst = cand_q + (size_t)(row - N_ROWS) * D_DIM;
  }

  float4 v = reinterpret_cast<const float4*>(src)[t];
  float ss = v.x * v.x + v.y * v.y + v.z * v.z + v.w * v.w;
#pragma unroll
  for (int m = 32; m >= 1; m >>= 1) ss += __shfl_xor(ss, m, 64);
  __shared__ float red[4];
  const int w = t >> 6, l = t & 63;
  if (l == 0) red[w] = ss;
  __syncthreads();
  const float tot = red[0] + red[1] + red[2] + red[3];
  const float scale = 1.0f / fmaxf(sqrtf(tot), 1e-8f);

  int pk = __builtin_amdgcn_cvt_pk_fp8_f32(v.x * scale, v.y * scale, 0, false);
  pk = __builtin_amdgcn_cvt_pk_fp8_f32(v.z * scale, v.w * scale, pk, true);
  *reinterpret_cast<unsigned*>(dst + t * 4) = (unsigned)pk;

  if (t == 0 && row < N_ROWS) rowsum[row] = 0.0f;
}

// ---------------------------------------------------------------------------
// Kernel 2: fused MX-fp8 GEMM + exp-rowsum. 256x256 tile, BK=64, 1024 thr =
// 16 waves (4Mx4N), per-wave 64x64 = 2x2 frags of mfma_scale_f32_32x32x64
// (unit scales 127 -> x1.0). acc = 4 named f32x16 (64 VGPR) so everything
// fits the 128 arch-VGPR region -- no spill (round-8 lesson). 4 LDS buffers,
// staged 2 tiles ahead (2 loads/thread/tile), one barrier per K-tile,
// counted vmcnt(2) (never 0 until tail). LDS 16B-slot rotation
// phys = (s + ((row>>1)&3)) & 3: all 8 4-bank spans distinct per 8-lane
// quantum -> conflict-free b128 reads.
// ---------------------------------------------------------------------------
__global__ __launch_bounds__(1024, 4) void gemm_lse_kernel(
    const unsigned char* __restrict__ s_q,
    const unsigned char* __restrict__ cand_q,
    float* __restrict__ rowsum, float* __restrict__ pos) {
  __shared__ __align__(16) unsigned char lds[131072];  // 4 x (A 16K | B 16K)

  const int t = threadIdx.x;
  const int w = t >> 6;
  const int l = t & 63;
  const int l31 = l & 31;
  const int h = l >> 5;        // k-half of the fragment
  const int wm4 = w >> 2;      // 0..3 (wave M quarter)
  const int wn4 = w & 3;       // 0..3 (wave N quarter)
  const int rowBase = blockIdx.y * BM;
  const int colBase = blockIdx.x * BN;

  // lane-constant phys slots for the two 16B reads of each 32B fragment:
  const int cc = (l31 >> 1) & 3;
  const int p0 = (h * 2 + cc) & 3;
  const int p1 = (h * 2 + 1 + cc) & 3;

  f32x16 acc00 = {}, acc01 = {}, acc10 = {}, acc11 = {};

  // staging: thread t -> phys slot (t&3) of local row (t>>2), linear LDS dst
  // t*16; fetch logical slot = (phys - ((row>>1)&3)) & 3.
  const int sRow = t >> 2;                      // 0..255
  const int sSlotL = ((t & 3) - (t >> 3)) & 3;  // logical slot to fetch
  const size_t gA0 = (size_t)(rowBase + sRow) * D_DIM + sSlotL * 16;
  const size_t gB0 = (size_t)(colBase + sRow) * D_DIM + sSlotL * 16;

  auto stage = [&](int T) {
    const unsigned char* sa = s_q + gA0 + T * 64;
    const unsigned char* sb = cand_q + gB0 + T * 64;
    unsigned char* da = lds + (T & 3) * 32768 + t * 16;
    __builtin_amdgcn_global_load_lds((const gvoid*)sa, (lvoid*)da, 16, 0, 0);
    __builtin_amdgcn_global_load_lds((const gvoid*)sb,
                                     (lvoid*)(da + 16384), 16, 0, 0);
  };

  auto ldfrag = [&](const unsigned char* base, int roff) -> i32x8 {
    const int r = roff + l31;
    i32x4 v0 = *reinterpret_cast<const i32x4*>(base + r * 64 + p0 * 16);
    i32x4 v1 = *reinterpret_cast<const i32x4*>(base + r * 64 + p1 * 16);
    return __builtin_shufflevector(v0, v1, 0, 1, 2, 3, 4, 5, 6, 7);
  };

  // --- prologue: stage tiles 0,1; wait tile 0 (tile 1's 2 stay in flight).
  stage(0); stage(1);
  asm volatile("s_waitcnt vmcnt(2)" ::: "memory");
  SCHED0();
  BAR(); SCHED0();

  for (int T = 0; T < NT; ++T) {
    const unsigned char* A = lds + (T & 3) * 32768;
    const unsigned char* B = A + 16384;
    i32x8 af0 = ldfrag(A, wm4 * 64);
    i32x8 af1 = ldfrag(A, wm4 * 64 + 32);
    i32x8 bf0 = ldfrag(B, wn4 * 64);
    i32x8 bf1 = ldfrag(B, wn4 * 64 + 32);
    if (T + 2 < NT) stage(T + 2);

    __builtin_amdgcn_s_setprio(1);
    acc00 = __builtin_amdgcn_mfma_scale_f32_32x32x64_f8f6f4(
        af0, bf0, acc00, 0, 0, 0, 127, 0, 127);
    acc01 = __builtin_amdgcn_mfma_scale_f32_32x32x64_f8f6f4(
        af0, bf1, acc01, 0, 0, 0, 127, 0, 127);
    acc10 = __builtin_amdgcn_mfma_scale_f32_32x32x64_f8f6f4(
        af1, bf0, acc10, 0, 0, 0, 127, 0, 127);
    acc11 = __builtin_amdgcn_mfma_scale_f32_32x32x64_f8f6f4(
        af1, bf1, acc11, 0, 0, 0, 127, 0, 127);
    __builtin_amdgcn_s_setprio(0);

    if (T <= NT - 3) {
      asm volatile("s_waitcnt vmcnt(2)" ::: "memory");  // T+1 landed
    } else if (T == NT - 2) {
      asm volatile("s_waitcnt vmcnt(0)" ::: "memory");  // tail drain
    }
    SCHED0();
    BAR(); SCHED0();
  }

  // --- epilogue: sim = acc*20; cosine<=1 -> fixed-max logsumexp at 20.
  // 32x32 C/D layout: col = l&31, row = (reg&3) + 8*(reg>>2) + 4*(l>>5).
  __syncthreads();
  float* red = reinterpret_cast<float*>(lds);
  if (t < 256) red[t] = 0.0f;
  __syncthreads();

  auto epi = [&](const f32x16& a, int m2, int n2) {
#pragma unroll
    for (int r = 0; r < 16; ++r) {
      const int rloc = wm4 * 64 + m2 * 32 + (r & 3) + 8 * (r >> 2) + 4 * h;
      const int rowg = rowBase + rloc;
      const int colg = colBase + wn4 * 64 + n2 * 32 + l31;
      const float simv = a[r] * TEMP_INV;
      if (colg == rowg) pos[rowg] = simv;
      float sm = __expf(simv - TEMP_INV);
      sm += __shfl_xor(sm, 1, 64);
      sm += __shfl_xor(sm, 2, 64);
      sm += __shfl_xor(sm, 4, 64);
      sm += __shfl_xor(sm, 8, 64);
      sm += __shfl_xor(sm, 16, 64);
      if (l31 == 0) atomicAdd(&red[rloc], sm);
    }
  };
  epi(acc00, 0, 0);
  epi(acc01, 0, 1);
  epi(acc10, 1, 0);
  epi(acc11, 1, 1);

  __syncthreads();
  if (t < 256) atomicAdd(&rowsum[rowBase + t], red[t]);
}

// ---------------------------------------------------------------------------
// Kernel 3: loss = mean(20 + log(rowsum) - pos)
// ---------------------------------------------------------------------------
__global__ __launch_bounds__(1024) void loss_kernel(
    const float* __restrict__ rowsum, const float* __restrict__ pos,
    float* __restrict__ out) {
  const int t = threadIdx.x;
  float acc = 0.0f;
  for (int i = t; i < N_ROWS; i += 1024)
    acc += TEMP_INV + logf(rowsum[i]) - pos[i];
#pragma unroll
  for (int m = 32; m >= 1; m >>= 1) acc += __shfl_xor(acc, m, 64);
  __shared__ float red[16];
  const int w = t >> 6, l = t & 63;
  if (l == 0) red[w] = acc;
  __syncthreads();
  if (t == 0) {
    float tot = 0.0f;
#pragma unroll
    for (int i = 0; i < 16; ++i) tot += red[i];
    out[0] = tot / (float)N_ROWS;
  }
}

// ---------------------------------------------------------------------------
extern "C" void kernel_launch(void* const* d_in, const int* in_sizes, int n_in,
                              void* d_out, int out_size, void* d_ws,
                              size_t ws_size, hipStream_t stream) {
  (void)in_sizes; (void)n_in; (void)out_size; (void)ws_size;
  const float* s = (const float*)d_in[0];
  const float* p = (const float*)d_in[1];
  const float* ng = (const float*)d_in[2];

  unsigned char* s_q = (unsigned char*)d_ws;                      // 4 MB
  unsigned char* cand_q = s_q + (size_t)N_ROWS * D_DIM;           // 8 MB
  float* rowsum = (float*)(cand_q + (size_t)N_CAND * D_DIM);      // 16 KB
  float* pos = rowsum + N_ROWS;                                   // 16 KB
  float* out = (float*)d_out;

  prep_kernel<<<dim3(3 * N_ROWS), dim3(256), 0, stream>>>(s, p, ng, s_q,
                                                          cand_q, rowsum);
  gemm_lse_kernel<<<dim3(N_CAND / BN, N_ROWS / BM), dim3(1024), 0, stream>>>(
      s_q, cand_q, rowsum, pos);
  loss_kernel<<<dim3(1), dim3(1024), 0, stream>>>(rowsum, pos, out);
}

// Round 10
// 275.827 us; speedup vs baseline: 1.9067x; 1.9067x over previous
//
#include <hip/hip_runtime.h>
#include <stdint.h>

#define N_ROWS 4096
#define D_DIM  1024
#define N_CAND 8192
#define TEMP_INV 20.0f

#define BM 128
#define BN 256
#define BK 64
#define NT 16        // K-tiles
#define BUFSZ 24576  // A(8K) + B(16K)

typedef __attribute__((ext_vector_type(4)))  int   i32x4;
typedef __attribute__((ext_vector_type(8)))  int   i32x8;
typedef __attribute__((ext_vector_type(16))) float f32x16;

using gvoid = __attribute__((address_space(1))) void;
using lvoid = __attribute__((address_space(3))) void;

#define BAR() __builtin_amdgcn_s_barrier()
#define SCHED0() __builtin_amdgcn_sched_barrier(0)

// ---------------------------------------------------------------------------
// Kernel 1: normalize rows, convert to fp8 e4m3 (natural column order).
// cand = [P; N]. Also zeroes rowsum.
// ---------------------------------------------------------------------------
__global__ __launch_bounds__(256) void prep_kernel(
    const float* __restrict__ s, const float* __restrict__ p,
    const float* __restrict__ ng, unsigned char* __restrict__ s_q,
    unsigned char* __restrict__ cand_q, float* __restrict__ rowsum) {
  const int row = blockIdx.x;
  const int t = threadIdx.x;
  const float* src;
  unsigned char* dst;
  if (row < N_ROWS) {
    src = s + (size_t)row * D_DIM;
    dst = s_q + (size_t)row * D_DIM;
  } else if (row < 2 * N_ROWS) {
    src = p + (size_t)(row - N_ROWS) * D_DIM;
    dst = cand_q + (size_t)(row - N_ROWS) * D_DIM;
  } else {
    src = ng + (size_t)(row - 2 * N_ROWS) * D_DIM;
    dst = cand_q + (size_t)(row - N_ROWS) * D_DIM;
  }

  float4 v = reinterpret_cast<const float4*>(src)[t];
  float ss = v.x * v.x + v.y * v.y + v.z * v.z + v.w * v.w;
#pragma unroll
  for (int m = 32; m >= 1; m >>= 1) ss += __shfl_xor(ss, m, 64);
  __shared__ float red[4];
  const int w = t >> 6, l = t & 63;
  if (l == 0) red[w] = ss;
  __syncthreads();
  const float tot = red[0] + red[1] + red[2] + red[3];
  const float scale = 1.0f / fmaxf(sqrtf(tot), 1e-8f);

  int pk = __builtin_amdgcn_cvt_pk_fp8_f32(v.x * scale, v.y * scale, 0, false);
  pk = __builtin_amdgcn_cvt_pk_fp8_f32(v.z * scale, v.w * scale, pk, true);
  *reinterpret_cast<unsigned*>(dst + t * 4) = (unsigned)pk;

  if (t == 0 && row < N_ROWS) rowsum[row] = 0.0f;
}

// ---------------------------------------------------------------------------
// Kernel 2: fused MX-fp8 GEMM + exp-rowsum. 128x256 block tile, BK=64,
// 512 thr = 8 waves (2Mx4N), per-wave 64x64 = 2x2 frags of
// mfma_scale_f32_32x32x64_f8f6f4 (unit scales 127 -> x1.0, verified
// rounds 8/9). Live regs ~130 << 256 budget (512,2) -> no spill.
// 3-buffer LDS ring (72 KB), staged 2 tiles ahead (3 loads/thread/tile),
// one barrier per K-tile, counted vmcnt(3) (0 only at tail). LDS 16B-slot
// rotation phys = (logical + ((row>>1)&3)) & 3; all ds_read offsets fold to
// immediates off 4 lane-constant bases (loop fully unrolled, T%3 constant).
// ---------------------------------------------------------------------------
__global__ __launch_bounds__(512, 2) void gemm_lse_kernel(
    const unsigned char* __restrict__ s_q,
    const unsigned char* __restrict__ cand_q,
    float* __restrict__ rowsum, float* __restrict__ pos) {
  __shared__ __align__(16) unsigned char lds[3 * BUFSZ];  // 72 KB

  const int t = threadIdx.x;
  const int w = t >> 6;
  const int l = t & 63;
  const int l31 = l & 31;
  const int h = l >> 5;     // k-half of the fragment
  const int wm = w >> 2;    // 0..1 (wave M half)
  const int wn = w & 3;     // 0..3 (wave N quarter)
  const int rowBase = blockIdx.y * BM;
  const int colBase = blockIdx.x * BN;

  // lane-constant phys slots for the two 16B reads of each 32B fragment:
  const int cc = (l31 >> 1) & 3;
  const int p0 = (2 * h + cc) & 3;
  const int p1 = (2 * h + 1 + cc) & 3;

  // lane-constant frag read bases (within a buffer):
  const int aOff0 = (wm * 64 + l31) * 64 + p0 * 16;
  const int aOff1 = (wm * 64 + l31) * 64 + p1 * 16;
  const int bOff0 = 8192 + (wn * 64 + l31) * 64 + p0 * 16;
  const int bOff1 = 8192 + (wn * 64 + l31) * 64 + p1 * 16;

  // staging: thread t -> phys slot (t&3) of local row (t>>2); linear LDS
  // dst t*16; fetch logical slot = (phys - ((row>>1)&3)) & 3.
  const int sRow = t >> 2;                      // 0..127
  const int sSlotL = ((t & 3) - (t >> 3)) & 3;  // logical slot to fetch
  const unsigned char* gA =
      s_q + (size_t)(rowBase + sRow) * D_DIM + sSlotL * 16;
  const unsigned char* gB0 =
      cand_q + (size_t)(colBase + sRow) * D_DIM + sSlotL * 16;
  const unsigned char* gB1 = gB0 + (size_t)128 * D_DIM;

  f32x16 acc00 = {}, acc01 = {}, acc10 = {}, acc11 = {};

  auto stage = [&](int T) {
    const int buf = (T % 3) * BUFSZ;
    __builtin_amdgcn_global_load_lds((const gvoid*)(gA + T * 64),
                                     (lvoid*)(lds + buf + t * 16), 16, 0, 0);
    __builtin_amdgcn_global_load_lds(
        (const gvoid*)(gB0 + T * 64),
        (lvoid*)(lds + buf + 8192 + t * 16), 16, 0, 0);
    __builtin_amdgcn_global_load_lds(
        (const gvoid*)(gB1 + T * 64),
        (lvoid*)(lds + buf + 16384 + t * 16), 16, 0, 0);
  };
  auto rd16 = [&](int off) -> i32x4 {
    return *reinterpret_cast<const i32x4*>(lds + off);
  };
  auto mk8 = [&](i32x4 a, i32x4 b) -> i32x8 {
    return __builtin_shufflevector(a, b, 0, 1, 2, 3, 4, 5, 6, 7);
  };

  // --- prologue: stage tiles 0,1; wait tile 0 (tile 1's 3 stay in flight).
  stage(0); stage(1);
  asm volatile("s_waitcnt vmcnt(3)" ::: "memory");
  SCHED0();
  BAR(); SCHED0();

#pragma unroll
  for (int T = 0; T < NT; ++T) {
    const int buf = (T % 3) * BUFSZ;
    i32x8 af0 = mk8(rd16(buf + aOff0), rd16(buf + aOff1));
    i32x8 af1 = mk8(rd16(buf + aOff0 + 2048), rd16(buf + aOff1 + 2048));
    i32x8 bf0 = mk8(rd16(buf + bOff0), rd16(buf + bOff1));
    i32x8 bf1 = mk8(rd16(buf + bOff0 + 2048), rd16(buf + bOff1 + 2048));
    if (T + 2 < NT) stage(T + 2);

    __builtin_amdgcn_s_setprio(1);
    acc00 = __builtin_amdgcn_mfma_scale_f32_32x32x64_f8f6f4(
        af0, bf0, acc00, 0, 0, 0, 127, 0, 127);
    acc01 = __builtin_amdgcn_mfma_scale_f32_32x32x64_f8f6f4(
        af0, bf1, acc01, 0, 0, 0, 127, 0, 127);
    acc10 = __builtin_amdgcn_mfma_scale_f32_32x32x64_f8f6f4(
        af1, bf0, acc10, 0, 0, 0, 127, 0, 127);
    acc11 = __builtin_amdgcn_mfma_scale_f32_32x32x64_f8f6f4(
        af1, bf1, acc11, 0, 0, 0, 127, 0, 127);
    __builtin_amdgcn_s_setprio(0);

    if (T <= NT - 3) {
      asm volatile("s_waitcnt vmcnt(3)" ::: "memory");  // T+1 landed
    } else if (T == NT - 2) {
      asm volatile("s_waitcnt vmcnt(0)" ::: "memory");  // tail drain
    }
    SCHED0();
    BAR(); SCHED0();
  }

  // --- epilogue: sim = acc*20; cosine<=1 -> fixed-max logsumexp at 20.
  // 32x32 C/D layout: col = l&31, row = (reg&3) + 8*(reg>>2) + 4*(l>>5).
  __syncthreads();
  float* red = reinterpret_cast<float*>(lds);
  if (t < BM) red[t] = 0.0f;
  __syncthreads();

  auto epi = [&](const f32x16& a, int m2, int n2) {
#pragma unroll
    for (int r = 0; r < 16; ++r) {
      const int rloc = wm * 64 + m2 * 32 + (r & 3) + 8 * (r >> 2) + 4 * h;
      const int rowg = rowBase + rloc;
      const int colg = colBase + wn * 64 + n2 * 32 + l31;
      const float simv = a[r] * TEMP_INV;
      if (colg == rowg) pos[rowg] = simv;
      float sm = __expf(simv - TEMP_INV);
      sm += __shfl_xor(sm, 1, 64);
      sm += __shfl_xor(sm, 2, 64);
      sm += __shfl_xor(sm, 4, 64);
      sm += __shfl_xor(sm, 8, 64);
      sm += __shfl_xor(sm, 16, 64);
      if (l31 == 0) atomicAdd(&red[rloc], sm);
    }
  };
  epi(acc00, 0, 0);
  epi(acc01, 0, 1);
  epi(acc10, 1, 0);
  epi(acc11, 1, 1);

  __syncthreads();
  if (t < BM) atomicAdd(&rowsum[rowBase + t], red[t]);
}

// ---------------------------------------------------------------------------
// Kernel 3: loss = mean(20 + log(rowsum) - pos)
// ---------------------------------------------------------------------------
__global__ __launch_bounds__(1024) void loss_kernel(
    const float* __restrict__ rowsum, const float* __restrict__ pos,
    float* __restrict__ out) {
  const int t = threadIdx.x;
  float acc = 0.0f;
  for (int i = t; i < N_ROWS; i += 1024)
    acc += TEMP_INV + logf(rowsum[i]) - pos[i];
#pragma unroll
  for (int m = 32; m >= 1; m >>= 1) acc += __shfl_xor(acc, m, 64);
  __shared__ float red[16];
  const int w = t >> 6, l = t & 63;
  if (l == 0) red[w] = acc;
  __syncthreads();
  if (t == 0) {
    float tot = 0.0f;
#pragma unroll
    for (int i = 0; i < 16; ++i) tot += red[i];
    out[0] = tot / (float)N_ROWS;
  }
}

// ---------------------------------------------------------------------------
extern "C" void kernel_launch(void* const* d_in, const int* in_sizes, int n_in,
                              void* d_out, int out_size, void* d_ws,
                              size_t ws_size, hipStream_t stream) {
  (void)in_sizes; (void)n_in; (void)out_size; (void)ws_size;
  const float* s = (const float*)d_in[0];
  const float* p = (const float*)d_in[1];
  const float* ng = (const float*)d_in[2];

  unsigned char* s_q = (unsigned char*)d_ws;                      // 4 MB
  unsigned char* cand_q = s_q + (size_t)N_ROWS * D_DIM;           // 8 MB
  float* rowsum = (float*)(cand_q + (size_t)N_CAND * D_DIM);      // 16 KB
  float* pos = rowsum + N_ROWS;                                   // 16 KB
  float* out = (float*)d_out;

  prep_kernel<<<dim3(3 * N_ROWS), dim3(256), 0, stream>>>(s, p, ng, s_q,
                                                          cand_q, rowsum);
  gemm_lse_kernel<<<dim3(N_CAND / BN, N_ROWS / BM), dim3(512), 0, stream>>>(
      s_q, cand_q, rowsum, pos);
  loss_kernel<<<dim3(1), dim3(1024), 0, stream>>>(rowsum, pos, out);
}

// Round 11
// 268.738 us; speedup vs baseline: 1.9570x; 1.0264x over previous
//
#include <hip/hip_runtime.h>
#include <stdint.h>

#define N_ROWS 4096
#define D_DIM  1024
#define N_CAND 8192
#define TEMP_INV 20.0f

#define BM 128
#define BN 256
#define BK 64
#define NT 16        // K-tiles
#define BUFSZ 24576  // A(8K) + B(16K)

typedef __attribute__((ext_vector_type(4)))  int   i32x4;
typedef __attribute__((ext_vector_type(8)))  int   i32x8;
typedef __attribute__((ext_vector_type(16))) float f32x16;

using gvoid = __attribute__((address_space(1))) void;
using lvoid = __attribute__((address_space(3))) void;

#define BAR() __builtin_amdgcn_s_barrier()
#define SCHED0() __builtin_amdgcn_sched_barrier(0)

// ---------------------------------------------------------------------------
// Kernel 1: normalize rows, convert to fp8 e4m3 (natural column order).
// cand = [P; N]. Also zeroes rowsum.
// ---------------------------------------------------------------------------
__global__ __launch_bounds__(256) void prep_kernel(
    const float* __restrict__ s, const float* __restrict__ p,
    const float* __restrict__ ng, unsigned char* __restrict__ s_q,
    unsigned char* __restrict__ cand_q, float* __restrict__ rowsum) {
  const int row = blockIdx.x;
  const int t = threadIdx.x;
  const float* src;
  unsigned char* dst;
  if (row < N_ROWS) {
    src = s + (size_t)row * D_DIM;
    dst = s_q + (size_t)row * D_DIM;
  } else if (row < 2 * N_ROWS) {
    src = p + (size_t)(row - N_ROWS) * D_DIM;
    dst = cand_q + (size_t)(row - N_ROWS) * D_DIM;
  } else {
    src = ng + (size_t)(row - 2 * N_ROWS) * D_DIM;
    dst = cand_q + (size_t)(row - N_ROWS) * D_DIM;
  }

  float4 v = reinterpret_cast<const float4*>(src)[t];
  float ss = v.x * v.x + v.y * v.y + v.z * v.z + v.w * v.w;
#pragma unroll
  for (int m = 32; m >= 1; m >>= 1) ss += __shfl_xor(ss, m, 64);
  __shared__ float red[4];
  const int w = t >> 6, l = t & 63;
  if (l == 0) red[w] = ss;
  __syncthreads();
  const float tot = red[0] + red[1] + red[2] + red[3];
  const float scale = 1.0f / fmaxf(sqrtf(tot), 1e-8f);

  int pk = __builtin_amdgcn_cvt_pk_fp8_f32(v.x * scale, v.y * scale, 0, false);
  pk = __builtin_amdgcn_cvt_pk_fp8_f32(v.z * scale, v.w * scale, pk, true);
  *reinterpret_cast<unsigned*>(dst + t * 4) = (unsigned)pk;

  if (t == 0 && row < N_ROWS) rowsum[row] = 0.0f;
}

// ---------------------------------------------------------------------------
// Kernel 2: fused MX-fp8 GEMM + exp-rowsum. 128x256 block tile, BK=64,
// 512 thr = 8 waves (2Mx4N), per-wave 64x64 = 2x2 frags of
// mfma_scale_f32_32x32x64_f8f6f4 (unit scales 127 -> x1.0; layout verified
// rounds 8-10, absmax 0.0). KEY CHANGE vs r10: __launch_bounds__(512) with
// NO occupancy request -- the mfma_scale path keeps C/D in arch VGPRs (no
// AGPR), and the declared-occupancy arch cap (128) was forcing loop spill
// (r8/r9/r10: 467MB/901MB/623MB scratch writes). Uncapped need is ~170.
// 4-buffer LDS ring (96KB), staged 2 tiles ahead (3 loads/thread/tile),
// one barrier per K-tile, counted vmcnt(3) (0 only at tail). LDS 16B-slot
// rotation phys = (logical + ((row>>1)&3)) & 3.
// ---------------------------------------------------------------------------
__global__ __launch_bounds__(512) void gemm_lse_kernel(
    const unsigned char* __restrict__ s_q,
    const unsigned char* __restrict__ cand_q,
    float* __restrict__ rowsum, float* __restrict__ pos) {
  __shared__ __align__(16) unsigned char lds[4 * BUFSZ];  // 96 KB

  const int t = threadIdx.x;
  const int w = t >> 6;
  const int l = t & 63;
  const int l31 = l & 31;
  const int h = l >> 5;     // k-half of the fragment
  const int wm = w >> 2;    // 0..1 (wave M half)
  const int wn = w & 3;     // 0..3 (wave N quarter)
  const int rowBase = blockIdx.y * BM;
  const int colBase = blockIdx.x * BN;

  // lane-constant phys slots for the two 16B reads of each 32B fragment:
  const int cc = (l31 >> 1) & 3;
  const int p0 = (2 * h + cc) & 3;
  const int p1 = (2 * h + 1 + cc) & 3;

  // lane-constant frag read bases (within a buffer):
  const int aOff0 = (wm * 64 + l31) * 64 + p0 * 16;
  const int aOff1 = (wm * 64 + l31) * 64 + p1 * 16;
  const int bOff0 = 8192 + (wn * 64 + l31) * 64 + p0 * 16;
  const int bOff1 = 8192 + (wn * 64 + l31) * 64 + p1 * 16;

  // staging: thread t -> phys slot (t&3) of local row (t>>2); linear LDS
  // dst t*16; fetch logical slot = (phys - ((row>>1)&3)) & 3.
  const int sRow = t >> 2;                      // 0..127
  const int sSlotL = ((t & 3) - (t >> 3)) & 3;  // logical slot to fetch
  const unsigned char* gA =
      s_q + (size_t)(rowBase + sRow) * D_DIM + sSlotL * 16;
  const unsigned char* gB0 =
      cand_q + (size_t)(colBase + sRow) * D_DIM + sSlotL * 16;
  const unsigned char* gB1 = gB0 + (size_t)128 * D_DIM;

  f32x16 acc00 = {}, acc01 = {}, acc10 = {}, acc11 = {};

  auto stage = [&](int T) {
    const int buf = (T & 3) * BUFSZ;
    __builtin_amdgcn_global_load_lds((const gvoid*)(gA + T * 64),
                                     (lvoid*)(lds + buf + t * 16), 16, 0, 0);
    __builtin_amdgcn_global_load_lds(
        (const gvoid*)(gB0 + T * 64),
        (lvoid*)(lds + buf + 8192 + t * 16), 16, 0, 0);
    __builtin_amdgcn_global_load_lds(
        (const gvoid*)(gB1 + T * 64),
        (lvoid*)(lds + buf + 16384 + t * 16), 16, 0, 0);
  };
  auto rd16 = [&](int off) -> i32x4 {
    return *reinterpret_cast<const i32x4*>(lds + off);
  };
  auto mk8 = [&](i32x4 a, i32x4 b) -> i32x8 {
    return __builtin_shufflevector(a, b, 0, 1, 2, 3, 4, 5, 6, 7);
  };

  // --- prologue: stage tiles 0,1; wait tile 0 (tile 1's 3 stay in flight).
  stage(0); stage(1);
  asm volatile("s_waitcnt vmcnt(3)" ::: "memory");
  SCHED0();
  BAR(); SCHED0();

#pragma unroll
  for (int T = 0; T < NT; ++T) {
    const int buf = (T & 3) * BUFSZ;
    i32x8 af0 = mk8(rd16(buf + aOff0), rd16(buf + aOff1));
    i32x8 af1 = mk8(rd16(buf + aOff0 + 2048), rd16(buf + aOff1 + 2048));
    i32x8 bf0 = mk8(rd16(buf + bOff0), rd16(buf + bOff1));
    i32x8 bf1 = mk8(rd16(buf + bOff0 + 2048), rd16(buf + bOff1 + 2048));
    if (T + 2 < NT) stage(T + 2);

    __builtin_amdgcn_s_setprio(1);
    acc00 = __builtin_amdgcn_mfma_scale_f32_32x32x64_f8f6f4(
        af0, bf0, acc00, 0, 0, 0, 127, 0, 127);
    acc01 = __builtin_amdgcn_mfma_scale_f32_32x32x64_f8f6f4(
        af0, bf1, acc01, 0, 0, 0, 127, 0, 127);
    acc10 = __builtin_amdgcn_mfma_scale_f32_32x32x64_f8f6f4(
        af1, bf0, acc10, 0, 0, 0, 127, 0, 127);
    acc11 = __builtin_amdgcn_mfma_scale_f32_32x32x64_f8f6f4(
        af1, bf1, acc11, 0, 0, 0, 127, 0, 127);
    __builtin_amdgcn_s_setprio(0);

    if (T <= NT - 3) {
      asm volatile("s_waitcnt vmcnt(3)" ::: "memory");  // T+1 landed
    } else if (T == NT - 2) {
      asm volatile("s_waitcnt vmcnt(0)" ::: "memory");  // tail drain
    }
    SCHED0();
    BAR(); SCHED0();
  }

  // --- epilogue: sim = acc*20; cosine<=1 -> fixed-max logsumexp at 20.
  // 32x32 C/D layout: col = l&31, row = (reg&3) + 8*(reg>>2) + 4*(l>>5).
  __syncthreads();
  float* red = reinterpret_cast<float*>(lds);
  if (t < BM) red[t] = 0.0f;
  __syncthreads();

  auto epi = [&](const f32x16& a, int m2, int n2) {
#pragma unroll
    for (int r = 0; r < 16; ++r) {
      const int rloc = wm * 64 + m2 * 32 + (r & 3) + 8 * (r >> 2) + 4 * h;
      const int rowg = rowBase + rloc;
      const int colg = colBase + wn * 64 + n2 * 32 + l31;
      const float simv = a[r] * TEMP_INV;
      if (colg == rowg) pos[rowg] = simv;
      float sm = __expf(simv - TEMP_INV);
      sm += __shfl_xor(sm, 1, 64);
      sm += __shfl_xor(sm, 2, 64);
      sm += __shfl_xor(sm, 4, 64);
      sm += __shfl_xor(sm, 8, 64);
      sm += __shfl_xor(sm, 16, 64);
      if (l31 == 0) atomicAdd(&red[rloc], sm);
    }
  };
  epi(acc00, 0, 0);
  epi(acc01, 0, 1);
  epi(acc10, 1, 0);
  epi(acc11, 1, 1);

  __syncthreads();
  if (t < BM) atomicAdd(&rowsum[rowBase + t], red[t]);
}

// ---------------------------------------------------------------------------
// Kernel 3: loss = mean(20 + log(rowsum) - pos)
// ---------------------------------------------------------------------------
__global__ __launch_bounds__(1024) void loss_kernel(
    const float* __restrict__ rowsum, const float* __restrict__ pos,
    float* __restrict__ out) {
  const int t = threadIdx.x;
  float acc = 0.0f;
  for (int i = t; i < N_ROWS; i += 1024)
    acc += TEMP_INV + logf(rowsum[i]) - pos[i];
#pragma unroll
  for (int m = 32; m >= 1; m >>= 1) acc += __shfl_xor(acc, m, 64);
  __shared__ float red[16];
  const int w = t >> 6, l = t & 63;
  if (l == 0) red[w] = acc;
  __syncthreads();
  if (t == 0) {
    float tot = 0.0f;
#pragma unroll
    for (int i = 0; i < 16; ++i) tot += red[i];
    out[0] = tot / (float)N_ROWS;
  }
}

// ---------------------------------------------------------------------------
extern "C" void kernel_launch(void* const* d_in, const int* in_sizes, int n_in,
                              void* d_out, int out_size, void* d_ws,
                              size_t ws_size, hipStream_t stream) {
  (void)in_sizes; (void)n_in; (void)out_size; (void)ws_size;
  const float* s = (const float*)d_in[0];
  const float* p = (const float*)d_in[1];
  const float* ng = (const float*)d_in[2];

  unsigned char* s_q = (unsigned char*)d_ws;                      // 4 MB
  unsigned char* cand_q = s_q + (size_t)N_ROWS * D_DIM;           // 8 MB
  float* rowsum = (float*)(cand_q + (size_t)N_CAND * D_DIM);      // 16 KB
  float* pos = rowsum + N_ROWS;                                   // 16 KB
  float* out = (float*)d_out;

  prep_kernel<<<dim3(3 * N_ROWS), dim3(256), 0, stream>>>(s, p, ng, s_q,
                                                          cand_q, rowsum);
  gemm_lse_kernel<<<dim3(N_CAND / BN, N_ROWS / BM), dim3(512), 0, stream>>>(
      s_q, cand_q, rowsum, pos);
  loss_kernel<<<dim3(1), dim3(1024), 0, stream>>>(rowsum, pos, out);
}

// Round 12
// 267.927 us; speedup vs baseline: 1.9629x; 1.0030x over previous
//
#include <hip/hip_runtime.h>
#include <stdint.h>

#define N_ROWS 4096
#define D_DIM  1024
#define N_CAND 8192
#define TEMP_INV 20.0f

#define BM 128
#define BN 256
#define BK 64
#define NT 16        // K-tiles
#define BUFSZ 24576  // A(8K) + B(16K)

typedef __attribute__((ext_vector_type(4)))  int   i32x4;
typedef __attribute__((ext_vector_type(8)))  int   i32x8;
typedef __attribute__((ext_vector_type(16))) float f32x16;

using gvoid = __attribute__((address_space(1))) void;
using lvoid = __attribute__((address_space(3))) void;

#define BAR() __builtin_amdgcn_s_barrier()
#define SCHED0() __builtin_amdgcn_sched_barrier(0)

// ---------------------------------------------------------------------------
// Kernel 1: normalize rows, convert to fp8 e4m3 (natural column order).
// cand = [P; N]. Also zeroes rowsum.
// ---------------------------------------------------------------------------
__global__ __launch_bounds__(256) void prep_kernel(
    const float* __restrict__ s, const float* __restrict__ p,
    const float* __restrict__ ng, unsigned char* __restrict__ s_q,
    unsigned char* __restrict__ cand_q, float* __restrict__ rowsum) {
  const int row = blockIdx.x;
  const int t = threadIdx.x;
  const float* src;
  unsigned char* dst;
  if (row < N_ROWS) {
    src = s + (size_t)row * D_DIM;
    dst = s_q + (size_t)row * D_DIM;
  } else if (row < 2 * N_ROWS) {
    src = p + (size_t)(row - N_ROWS) * D_DIM;
    dst = cand_q + (size_t)(row - N_ROWS) * D_DIM;
  } else {
    src = ng + (size_t)(row - 2 * N_ROWS) * D_DIM;
    dst = cand_q + (size_t)(row - N_ROWS) * D_DIM;
  }

  float4 v = reinterpret_cast<const float4*>(src)[t];
  float ss = v.x * v.x + v.y * v.y + v.z * v.z + v.w * v.w;
#pragma unroll
  for (int m = 32; m >= 1; m >>= 1) ss += __shfl_xor(ss, m, 64);
  __shared__ float red[4];
  const int w = t >> 6, l = t & 63;
  if (l == 0) red[w] = ss;
  __syncthreads();
  const float tot = red[0] + red[1] + red[2] + red[3];
  const float scale = 1.0f / fmaxf(sqrtf(tot), 1e-8f);

  int pk = __builtin_amdgcn_cvt_pk_fp8_f32(v.x * scale, v.y * scale, 0, false);
  pk = __builtin_amdgcn_cvt_pk_fp8_f32(v.z * scale, v.w * scale, pk, true);
  *reinterpret_cast<unsigned*>(dst + t * 4) = (unsigned)pk;

  if (t == 0 && row < N_ROWS) rowsum[row] = 0.0f;
}

// ---------------------------------------------------------------------------
// Kernel 2: fused MX-fp8 GEMM + exp-rowsum. 128x256 tile, BK=64, 512 thr =
// 8 waves (2Mx4N), wave 64x64 = 2x2 frags of mfma_scale_f32_32x32x64_f8f6f4
// (unit scales 127 -> x1.0; layout verified r8-r11, absmax 0.0).
// REGISTER FIT (the r8-r11 lesson): the 128-arch-VGPR pin at 512-thread
// blocks is invariant; fit under it. acc 64 + af0/af1 16 + single bf 8
// (reloaded per n-half) + addr ~20 = ~110 < 128. No #pragma unroll (r7,
// which never spilled, was non-unrolled). 3-buffer LDS ring (72 KB) via
// rotating uniform offsets -> 2 blocks/CU at 128 VGPR. Staged 2 tiles
// ahead (3 loads/thread/tile), one barrier per K-tile, counted vmcnt(3)
// (0 only at tail). LDS 16B-slot rotation phys=(logical+((row>>1)&3))&3.
// ---------------------------------------------------------------------------
__global__ __launch_bounds__(512) void gemm_lse_kernel(
    const unsigned char* __restrict__ s_q,
    const unsigned char* __restrict__ cand_q,
    float* __restrict__ rowsum, float* __restrict__ pos) {
  __shared__ __align__(16) unsigned char lds[3 * BUFSZ];  // 72 KB

  const int t = threadIdx.x;
  const int w = t >> 6;
  const int l = t & 63;
  const int l31 = l & 31;
  const int h = l >> 5;     // k-half of the fragment
  const int wm = w >> 2;    // 0..1 (wave M half)
  const int wn = w & 3;     // 0..3 (wave N quarter)
  const int rowBase = blockIdx.y * BM;
  const int colBase = blockIdx.x * BN;

  // lane-constant phys slots for the two 16B reads of each 32B fragment:
  const int cc = (l31 >> 1) & 3;
  const int p0 = (2 * h + cc) & 3;
  const int p1 = (2 * h + 1 + cc) & 3;

  // lane-constant frag read bases (within a buffer):
  const int aOff0 = (wm * 64 + l31) * 64 + p0 * 16;
  const int aOff1 = (wm * 64 + l31) * 64 + p1 * 16;
  const int bOff0 = 8192 + (wn * 64 + l31) * 64 + p0 * 16;
  const int bOff1 = 8192 + (wn * 64 + l31) * 64 + p1 * 16;

  // staging: thread t -> phys slot (t&3) of local row (t>>2); linear LDS
  // dst t*16; fetch logical slot = (phys - ((row>>1)&3)) & 3.
  const int sRow = t >> 2;                      // 0..127
  const int sSlotL = ((t & 3) - (t >> 3)) & 3;  // logical slot to fetch
  const unsigned char* gA =
      s_q + (size_t)(rowBase + sRow) * D_DIM + sSlotL * 16;
  const unsigned char* gB0 =
      cand_q + (size_t)(colBase + sRow) * D_DIM + sSlotL * 16;
  const unsigned char* gB1 = gB0 + (size_t)128 * D_DIM;

  f32x16 acc00 = {}, acc01 = {}, acc10 = {}, acc11 = {};

  auto stage = [&](int T, int bufOff) {
    __builtin_amdgcn_global_load_lds((const gvoid*)(gA + T * 64),
                                     (lvoid*)(lds + bufOff + t * 16),
                                     16, 0, 0);
    __builtin_amdgcn_global_load_lds((const gvoid*)(gB0 + T * 64),
                                     (lvoid*)(lds + bufOff + 8192 + t * 16),
                                     16, 0, 0);
    __builtin_amdgcn_global_load_lds((const gvoid*)(gB1 + T * 64),
                                     (lvoid*)(lds + bufOff + 16384 + t * 16),
                                     16, 0, 0);
  };
  auto rd16 = [&](int off) -> i32x4 {
    return *reinterpret_cast<const i32x4*>(lds + off);
  };
  auto mk8 = [&](i32x4 a, i32x4 b) -> i32x8 {
    return __builtin_shufflevector(a, b, 0, 1, 2, 3, 4, 5, 6, 7);
  };

  // --- prologue: stage tiles 0,1; wait tile 0 (tile 1's 3 stay in flight).
  int bA = 0, bB = BUFSZ, bC = 2 * BUFSZ;  // uniform ring offsets (SGPR)
  stage(0, bA); stage(1, bB);
  asm volatile("s_waitcnt vmcnt(3)" ::: "memory");
  SCHED0();
  BAR(); SCHED0();

  for (int T = 0; T < NT; ++T) {
    i32x8 af0 = mk8(rd16(bA + aOff0), rd16(bA + aOff1));
    i32x8 af1 = mk8(rd16(bA + aOff0 + 2048), rd16(bA + aOff1 + 2048));
    if (T + 2 < NT) stage(T + 2, bC);

    i32x8 bf = mk8(rd16(bA + bOff0), rd16(bA + bOff1));
    __builtin_amdgcn_s_setprio(1);
    acc00 = __builtin_amdgcn_mfma_scale_f32_32x32x64_f8f6f4(
        af0, bf, acc00, 0, 0, 0, 127, 0, 127);
    acc10 = __builtin_amdgcn_mfma_scale_f32_32x32x64_f8f6f4(
        af1, bf, acc10, 0, 0, 0, 127, 0, 127);
    __builtin_amdgcn_s_setprio(0);

    bf = mk8(rd16(bA + bOff0 + 2048), rd16(bA + bOff1 + 2048));
    __builtin_amdgcn_s_setprio(1);
    acc01 = __builtin_amdgcn_mfma_scale_f32_32x32x64_f8f6f4(
        af0, bf, acc01, 0, 0, 0, 127, 0, 127);
    acc11 = __builtin_amdgcn_mfma_scale_f32_32x32x64_f8f6f4(
        af1, bf, acc11, 0, 0, 0, 127, 0, 127);
    __builtin_amdgcn_s_setprio(0);

    if (T <= NT - 3) {
      asm volatile("s_waitcnt vmcnt(3)" ::: "memory");  // T+1 landed
    } else if (T == NT - 2) {
      asm volatile("s_waitcnt vmcnt(0)" ::: "memory");  // tail drain
    }
    SCHED0();
    BAR(); SCHED0();

    const int tmp = bA; bA = bB; bB = bC; bC = tmp;  // rotate ring
  }

  // --- epilogue: sim = acc*20; cosine<=1 -> fixed-max logsumexp at 20.
  // 32x32 C/D layout: col = l&31, row = (reg&3) + 8*(reg>>2) + 4*(l>>5).
  __syncthreads();
  float* red = reinterpret_cast<float*>(lds);
  if (t < BM) red[t] = 0.0f;
  __syncthreads();

  auto epi = [&](const f32x16& a, int m2, int n2) {
#pragma unroll
    for (int r = 0; r < 16; ++r) {
      const int rloc = wm * 64 + m2 * 32 + (r & 3) + 8 * (r >> 2) + 4 * h;
      const int rowg = rowBase + rloc;
      const int colg = colBase + wn * 64 + n2 * 32 + l31;
      const float simv = a[r] * TEMP_INV;
      if (colg == rowg) pos[rowg] = simv;
      float sm = __expf(simv - TEMP_INV);
      sm += __shfl_xor(sm, 1, 64);
      sm += __shfl_xor(sm, 2, 64);
      sm += __shfl_xor(sm, 4, 64);
      sm += __shfl_xor(sm, 8, 64);
      sm += __shfl_xor(sm, 16, 64);
      if (l31 == 0) atomicAdd(&red[rloc], sm);
    }
  };
  epi(acc00, 0, 0);
  epi(acc01, 0, 1);
  epi(acc10, 1, 0);
  epi(acc11, 1, 1);

  __syncthreads();
  if (t < BM) atomicAdd(&rowsum[rowBase + t], red[t]);
}

// ---------------------------------------------------------------------------
// Kernel 3: loss = mean(20 + log(rowsum) - pos)
// ---------------------------------------------------------------------------
__global__ __launch_bounds__(1024) void loss_kernel(
    const float* __restrict__ rowsum, const float* __restrict__ pos,
    float* __restrict__ out) {
  const int t = threadIdx.x;
  float acc = 0.0f;
  for (int i = t; i < N_ROWS; i += 1024)
    acc += TEMP_INV + logf(rowsum[i]) - pos[i];
#pragma unroll
  for (int m = 32; m >= 1; m >>= 1) acc += __shfl_xor(acc, m, 64);
  __shared__ float red[16];
  const int w = t >> 6, l = t & 63;
  if (l == 0) red[w] = acc;
  __syncthreads();
  if (t == 0) {
    float tot = 0.0f;
#pragma unroll
    for (int i = 0; i < 16; ++i) tot += red[i];
    out[0] = tot / (float)N_ROWS;
  }
}

// ---------------------------------------------------------------------------
extern "C" void kernel_launch(void* const* d_in, const int* in_sizes, int n_in,
                              void* d_out, int out_size, void* d_ws,
                              size_t ws_size, hipStream_t stream) {
  (void)in_sizes; (void)n_in; (void)out_size; (void)ws_size;
  const float* s = (const float*)d_in[0];
  const float* p = (const float*)d_in[1];
  const float* ng = (const float*)d_in[2];

  unsigned char* s_q = (unsigned char*)d_ws;                      // 4 MB
  unsigned char* cand_q = s_q + (size_t)N_ROWS * D_DIM;           // 8 MB
  float* rowsum = (float*)(cand_q + (size_t)N_CAND * D_DIM);      // 16 KB
  float* pos = rowsum + N_ROWS;                                   // 16 KB
  float* out = (float*)d_out;

  prep_kernel<<<dim3(3 * N_ROWS), dim3(256), 0, stream>>>(s, p, ng, s_q,
                                                          cand_q, rowsum);
  gemm_lse_kernel<<<dim3(N_CAND / BN, N_ROWS / BM), dim3(512), 0, stream>>>(
      s_q, cand_q, rowsum, pos);
  loss_kernel<<<dim3(1), dim3(1024), 0, stream>>>(rowsum, pos, out);
}

// Round 13
// 64.417 us; speedup vs baseline: 8.1642x; 4.1593x over previous
//
#include <hip/hip_runtime.h>
#include <stdint.h>

#define N_ROWS 4096
#define D_DIM  1024
#define N_CAND 8192
#define TEMP_INV 20.0f
#define QSCALE 508.0f
#define OUT_SCALE (TEMP_INV / (QSCALE * QSCALE))

#define BM 256
#define BN 256
#define BK 64
#define NT 16  // K-tiles

typedef __attribute__((ext_vector_type(4))) int   i32x4;

using gvoid = __attribute__((address_space(1))) void;
using lvoid = __attribute__((address_space(3))) void;

#define BAR() __builtin_amdgcn_s_barrier()
#define SCHED0() __builtin_amdgcn_sched_barrier(0)

// ---------------------------------------------------------------------------
// Kernel 1: normalize rows, quantize to int8 (q = rint(x*508), clamp +-127),
// NATURAL column order (i8 16x16x64 fragment = 16 contiguous bytes).
// cand = [P; N]. Also zeroes rowsum.
// ---------------------------------------------------------------------------
__global__ __launch_bounds__(256) void prep_kernel(
    const float* __restrict__ s, const float* __restrict__ p,
    const float* __restrict__ ng, unsigned char* __restrict__ s_q,
    unsigned char* __restrict__ cand_q, float* __restrict__ rowsum) {
  const int row = blockIdx.x;
  const int t = threadIdx.x;
  const float* src;
  unsigned char* dst;
  if (row < N_ROWS) {
    src = s + (size_t)row * D_DIM;
    dst = s_q + (size_t)row * D_DIM;
  } else if (row < 2 * N_ROWS) {
    src = p + (size_t)(row - N_ROWS) * D_DIM;
    dst = cand_q + (size_t)(row - N_ROWS) * D_DIM;
  } else {
    src = ng + (size_t)(row - 2 * N_ROWS) * D_DIM;
    dst = cand_q + (size_t)(row - N_ROWS) * D_DIM;
  }

  float4 v = reinterpret_cast<const float4*>(src)[t];
  float ss = v.x * v.x + v.y * v.y + v.z * v.z + v.w * v.w;
#pragma unroll
  for (int m = 32; m >= 1; m >>= 1) ss += __shfl_xor(ss, m, 64);
  __shared__ float red[4];
  const int w = t >> 6, l = t & 63;
  if (l == 0) red[w] = ss;
  __syncthreads();
  const float tot = red[0] + red[1] + red[2] + red[3];
  const float qs = QSCALE / fmaxf(sqrtf(tot), 1e-8f);

  auto q8 = [&](float x) -> unsigned {
    return (unsigned)((int)rintf(fminf(fmaxf(x * qs, -127.0f), 127.0f))) &
           0xffu;
  };
  const unsigned pk =
      q8(v.x) | (q8(v.y) << 8) | (q8(v.z) << 16) | (q8(v.w) << 24);
  *reinterpret_cast<unsigned*>(dst + t * 4) = pk;

  if (t == 0 && row < N_ROWS) rowsum[row] = 0.0f;
}

// ---------------------------------------------------------------------------
// Kernel 2: fused i8 GEMM + exp-rowsum. 256x256 tile, BK=64, 512 thr =
// 8 waves (2Mx4N), wave 128x64 = 8x4 frags of mfma_i32_16x16x64_i8 (plain
// MFMA -> acc in AGPRs, the r5-r7 no-spill path; 2x fp8 rate). Per K-tile
// per wave: 12 ds_read_b128 + 32 MFMA. 4-buffer LDS ring (128 KB), staged
// 2 tiles ahead (4 loads/thread/tile), ONE barrier per K-tile, counted
// vmcnt(4) (0 only at tail). LDS 16B-slot rotation phys=(g+(rl>>1))&3
// (r7-verified conflict-free: 8 distinct 4-bank spans per 8-lane quantum);
// staging inverse-permutes the global source, LDS dst linear.
// ---------------------------------------------------------------------------
__global__ __launch_bounds__(512) void gemm_lse_kernel(
    const unsigned char* __restrict__ s_q,
    const unsigned char* __restrict__ cand_q,
    float* __restrict__ rowsum, float* __restrict__ pos) {
  __shared__ __align__(16) unsigned char lds[4 * 32768];  // 4 x (A16K|B16K)

  const int t = threadIdx.x;
  const int w = t >> 6;
  const int l = t & 63;
  const int g = l >> 4;    // k-slice group: lane's 16B = k g*16..g*16+15
  const int rl = l & 15;   // lane within group
  const int wm = w >> 2;   // 0..1 (wave M half)
  const int wn = w & 3;    // 0..3 (wave N quarter)
  const int slot = (g + (rl >> 1)) & 3;  // phys 16B-slot, lane-constant
  const int rowBase = blockIdx.y * BM;
  const int colBase = blockIdx.x * BN;

  i32x4 acc[8][4] = {};  // 128 AGPR (plain-MFMA path)
  i32x4 af[8];
  i32x4 bf[4];

  // staging: thread t -> phys slot (t&3) of local row (t>>2), linear LDS
  // dst t*16; fetch logical slot = ((t&3) - (t>>3)) & 3  (r7-verified).
  const int sRow = t >> 2;                      // 0..127
  const int sSlotL = ((t & 3) - (t >> 3)) & 3;  // logical slot to fetch
  const unsigned char* gA =
      s_q + (size_t)(rowBase + sRow) * D_DIM + sSlotL * 16;
  const unsigned char* gB =
      cand_q + (size_t)(colBase + sRow) * D_DIM + sSlotL * 16;

  auto stage = [&](int T) {
    const int buf = (T & 3) * 32768;
    const size_t ko = (size_t)T * 64;
#pragma unroll
    for (int h = 0; h < 2; ++h) {
      __builtin_amdgcn_global_load_lds(
          (const gvoid*)(gA + ko + (size_t)h * (128 * D_DIM)),
          (lvoid*)(lds + buf + h * 8192 + t * 16), 16, 0, 0);
      __builtin_amdgcn_global_load_lds(
          (const gvoid*)(gB + ko + (size_t)h * (128 * D_DIM)),
          (lvoid*)(lds + buf + 16384 + h * 8192 + t * 16), 16, 0, 0);
    }
  };

  // --- prologue: stage tiles 0,1; wait tile 0 (tile 1's 4 stay in flight).
  stage(0); stage(1);
  asm volatile("s_waitcnt vmcnt(4)" ::: "memory");
  SCHED0();
  BAR(); SCHED0();

  for (int T = 0; T < NT; ++T) {
    const unsigned char* A = lds + (T & 3) * 32768;
    const unsigned char* B = A + 16384;
#pragma unroll
    for (int m = 0; m < 8; ++m) {
      const int r = wm * 128 + m * 16 + rl;
      af[m] = *reinterpret_cast<const i32x4*>(A + r * 64 + slot * 16);
    }
#pragma unroll
    for (int n = 0; n < 4; ++n) {
      const int r = wn * 64 + n * 16 + rl;
      bf[n] = *reinterpret_cast<const i32x4*>(B + r * 64 + slot * 16);
    }
    if (T + 2 < NT) stage(T + 2);

    __builtin_amdgcn_s_setprio(1);
#pragma unroll
    for (int m = 0; m < 8; ++m)
#pragma unroll
      for (int n = 0; n < 4; ++n)
        acc[m][n] = __builtin_amdgcn_mfma_i32_16x16x64_i8(
            af[m], bf[n], acc[m][n], 0, 0, 0);
    __builtin_amdgcn_s_setprio(0);

    if (T <= NT - 3) {
      asm volatile("s_waitcnt vmcnt(4)" ::: "memory");  // T+1 landed
    } else if (T == NT - 2) {
      asm volatile("s_waitcnt vmcnt(0)" ::: "memory");  // tail drain
    }
    SCHED0();
    BAR(); SCHED0();
  }

  // --- epilogue: sim = acc * 20/508^2; cosine<=1 -> fixed-max LSE at 20.
  // i32 16x16 C/D layout (dtype-independent): col = l&15, row = g*4 + reg.
  __syncthreads();
  float* red = reinterpret_cast<float*>(lds);
  if (t < BM) red[t] = 0.0f;
  __syncthreads();

#pragma unroll
  for (int m = 0; m < 8; ++m) {
#pragma unroll
    for (int j = 0; j < 4; ++j) {
      const int rloc = wm * 128 + m * 16 + g * 4 + j;
      const int rowg = rowBase + rloc;
      float sm = 0.0f;
#pragma unroll
      for (int n = 0; n < 4; ++n) {
        const int colg = colBase + wn * 64 + n * 16 + rl;
        const float simv = (float)acc[m][n][j] * OUT_SCALE;
        if (colg == rowg) pos[rowg] = simv;
        sm += __expf(simv - TEMP_INV);
      }
      sm += __shfl_xor(sm, 1, 64);
      sm += __shfl_xor(sm, 2, 64);
      sm += __shfl_xor(sm, 4, 64);
      sm += __shfl_xor(sm, 8, 64);
      if (rl == 0) atomicAdd(&red[rloc], sm);
    }
  }
  __syncthreads();
  if (t < BM) atomicAdd(&rowsum[rowBase + t], red[t]);
}

// ---------------------------------------------------------------------------
// Kernel 3: loss = mean(20 + log(rowsum) - pos)
// ---------------------------------------------------------------------------
__global__ __launch_bounds__(1024) void loss_kernel(
    const float* __restrict__ rowsum, const float* __restrict__ pos,
    float* __restrict__ out) {
  const int t = threadIdx.x;
  float acc = 0.0f;
  for (int i = t; i < N_ROWS; i += 1024)
    acc += TEMP_INV + logf(rowsum[i]) - pos[i];
#pragma unroll
  for (int m = 32; m >= 1; m >>= 1) acc += __shfl_xor(acc, m, 64);
  __shared__ float red[16];
  const int w = t >> 6, l = t & 63;
  if (l == 0) red[w] = acc;
  __syncthreads();
  if (t == 0) {
    float tot = 0.0f;
#pragma unroll
    for (int i = 0; i < 16; ++i) tot += red[i];
    out[0] = tot / (float)N_ROWS;
  }
}

// ---------------------------------------------------------------------------
extern "C" void kernel_launch(void* const* d_in, const int* in_sizes, int n_in,
                              void* d_out, int out_size, void* d_ws,
                              size_t ws_size, hipStream_t stream) {
  (void)in_sizes; (void)n_in; (void)out_size; (void)ws_size;
  const float* s = (const float*)d_in[0];
  const float* p = (const float*)d_in[1];
  const float* ng = (const float*)d_in[2];

  unsigned char* s_q = (unsigned char*)d_ws;                      // 4 MB
  unsigned char* cand_q = s_q + (size_t)N_ROWS * D_DIM;           // 8 MB
  float* rowsum = (float*)(cand_q + (size_t)N_CAND * D_DIM);      // 16 KB
  float* pos = rowsum + N_ROWS;                                   // 16 KB
  float* out = (float*)d_out;

  prep_kernel<<<dim3(3 * N_ROWS), dim3(256), 0, stream>>>(s, p, ng, s_q,
                                                          cand_q, rowsum);
  gemm_lse_kernel<<<dim3(N_CAND / BN, N_ROWS / BM), dim3(512), 0, stream>>>(
      s_q, cand_q, rowsum, pos);
  loss_kernel<<<dim3(1), dim3(1024), 0, stream>>>(rowsum, pos, out);
}